// Round 3
// baseline (1899.682 us; speedup 1.0000x reference)
//
#include <hip/hip_runtime.h>

#define B_ 64
#define T_ 512
#define D_ 1024
#define C_ 32
#define NEG_INF (-1e30f)

__device__ __forceinline__ float bcast0(float v) {
  return __uint_as_float(__builtin_amdgcn_readfirstlane(__float_as_uint(v)));
}

// ---------------- logits = vectors @ W^T + b (f32, sequential-k fma chain) ----------------
// grid 256, block 256. Block tile: 128 rows x 32 cols. Thread: 4 rows (stride 32) x 4 cols (stride 8).
__global__ __launch_bounds__(256) void k_logits(const float* __restrict__ vec,
                                                const float* __restrict__ W,
                                                const float* __restrict__ bias,
                                                float* __restrict__ out) {
  const int tid = threadIdx.x;
  const int cg = tid & 7;   // col base 0..7  (cols cg + 8*cc)
  const int rg = tid >> 3;  // 0..31          (rows r0 + rg + 32*rr)
  const int r0 = blockIdx.x * 128;
  float acc[4][4];
#pragma unroll
  for (int a = 0; a < 4; ++a)
#pragma unroll
    for (int bb = 0; bb < 4; ++bb) acc[a][bb] = 0.f;
  const float* vb = vec + (size_t)(r0 + rg) * D_;
  const float* wb = W + (size_t)cg * D_;
#pragma unroll 4
  for (int k = 0; k < D_; k += 4) {
    float4 v[4], w[4];
#pragma unroll
    for (int rr = 0; rr < 4; ++rr) v[rr] = *(const float4*)(vb + (size_t)rr * 32 * D_ + k);
#pragma unroll
    for (int cc = 0; cc < 4; ++cc) w[cc] = *(const float4*)(wb + (size_t)cc * 8 * D_ + k);
#pragma unroll
    for (int rr = 0; rr < 4; ++rr)
#pragma unroll
      for (int cc = 0; cc < 4; ++cc) {
        acc[rr][cc] = fmaf(v[rr].x, w[cc].x, acc[rr][cc]);
        acc[rr][cc] = fmaf(v[rr].y, w[cc].y, acc[rr][cc]);
        acc[rr][cc] = fmaf(v[rr].z, w[cc].z, acc[rr][cc]);
        acc[rr][cc] = fmaf(v[rr].w, w[cc].w, acc[rr][cc]);
      }
  }
#pragma unroll
  for (int rr = 0; rr < 4; ++rr) {
    const size_t row = (size_t)(r0 + rg + rr * 32);
#pragma unroll
    for (int cc = 0; cc < 4; ++cc) {
      const int c = cg + cc * 8;
      out[row * C_ + c] = acc[rr][cc] + bias[c];  // b32 store: out base only 4B-aligned
    }
  }
}

// ---------------- CRF: forward(+score) and Viterbi(+backtrace) ----------------
// grid 128 x 64 threads (one wave64 per block -> LDS in-order, no barriers).
// blocks 0..63: forward in SCALED-PROBABILITY space (exp/log-free chain), with
//   each lane computing the FULL 32-term fma sum (ET[32] per lane; no cross-
//   lane exchange on the chain). Validated R2: loss/logits passed.
// blocks 64..127: f32 Viterbi — each lane computes the FULL 32-candidate
//   argmax via a 5-level pairwise tree whose left child always has the lower
//   index; strict 'right > left' at every node == np.argmax first-index ties
//   (max-with-first-index-tiebreak is associative). Candidate values are the
//   same plain f32 adds dd[i]+TT[i] as the np reference -> bit-exact tags.
//   NO permlane/shfl on the chain (R2's permlane asm was an allocation-hazard
//   and corrupted tags; removed entirely).
__global__ __launch_bounds__(64) void k_crf(const float* __restrict__ lg,
                                            const int* __restrict__ mask,
                                            const int* __restrict__ tgt,
                                            const float* __restrict__ trans,
                                            const float* __restrict__ st,
                                            const float* __restrict__ et,
                                            float* __restrict__ wsp,
                                            float* __restrict__ tags_out,
                                            float* __restrict__ path_out) {
  __shared__ __align__(16) float a_sh[C_];
  __shared__ __align__(16) float f_sh[C_];
  __shared__ __align__(16) float Lsh[2][64 * C_];  // role0: exp(lc-lc0) factors; role1: raw logits
  __shared__ float s0_sh[T_];
  __shared__ int mk_sh[T_];
  __shared__ unsigned char bp[(T_ - 1) * C_];
  __shared__ unsigned char tagb[T_];
  __shared__ unsigned char c8[64 * C_];
  __shared__ int btag[64];

  const int tid = threadIdx.x;
  const int b = blockIdx.x & 63;
  const int role = blockIdx.x >> 6;
  const int j = tid & 31;
  const float* L = lg + (size_t)b * T_ * C_;
  const int* mk = mask + b * T_;

  // ---- load chunk 0 (rows 0..63) to regs + full mask into LDS ----
  float pre[32];
#pragma unroll
  for (int i = 0; i < 32; ++i) pre[i] = L[i * 64 + tid];
  {
    int4 m0 = *(const int4*)(mk + tid * 4);
    int4 m1 = *(const int4*)(mk + 256 + tid * 4);
    *(int4*)&mk_sh[tid * 4] = m0;
    *(int4*)&mk_sh[256 + tid * 4] = m1;
  }

  if (role == 0) {
    // ================= forward (scaled-prob space) + score =================
    float ET[32];
#pragma unroll
    for (int i = 0; i < 32; ++i) ET[i] = __expf(trans[i * C_ + j]);
    // init: alpha0 = st + L[0]; m0 = alpha0[0]; p = exp(alpha0 - m0)
    const float a0j = st[j] + L[j];
    const float m0 = bcast0(a0j);
    float p = (tid < 32) ? __expf(a0j - m0) : 0.f;
    // chunk 0 -> F factors. element e=i*64+tid: row=(e>>5), col=e&31; row-base
    // (col 0) lives in lane 0 (tid<32) / lane 32 (tid>=32) of pre[i].
#pragma unroll
    for (int i = 0; i < 32; ++i) {
      const float b0 = __uint_as_float(__builtin_amdgcn_readfirstlane(__float_as_uint(pre[i])));
      const float b1 = __uint_as_float(__builtin_amdgcn_readlane(__float_as_uint(pre[i]), 32));
      const float base = (tid < 32) ? b0 : b1;
      Lsh[0][i * 64 + tid] = __expf(pre[i] - base);
    }
    for (int c = 0; c < 8; ++c) {
      if (c < 7) {  // issue next chunk's global loads before computing this chunk
#pragma unroll
        for (int i = 0; i < 32; ++i) pre[i] = L[(c + 1) * 2048 + i * 64 + tid];
      }
      const float* Fs = Lsh[c & 1];
      const int tlo = c ? c * 64 : 1;
      const int thi = c * 64 + 64;
      for (int t = tlo; t < thi; ++t) {
        const float Fv = Fs[(t - c * 64) * C_ + j];  // off-chain
        const int mc = mk_sh[t];                     // off-chain
        if (tid < 32) a_sh[j] = p;                   // chain: LDS round trip
        float av[32];
#pragma unroll
        for (int i = 0; i < 8; ++i) {
          float4 q = *(const float4*)&a_sh[i * 4];
          av[i * 4 + 0] = q.x; av[i * 4 + 1] = q.y;
          av[i * 4 + 2] = q.z; av[i * 4 + 3] = q.w;
        }
        float s0 = av[0] * ET[0], s1 = av[1] * ET[1], s2 = av[2] * ET[2], s3 = av[3] * ET[3];
#pragma unroll
        for (int q = 1; q < 8; ++q) {
          s0 = fmaf(av[4 * q + 0], ET[4 * q + 0], s0);
          s1 = fmaf(av[4 * q + 1], ET[4 * q + 1], s1);
          s2 = fmaf(av[4 * q + 2], ET[4 * q + 2], s2);
          s3 = fmaf(av[4 * q + 3], ET[4 * q + 3], s3);
        }
        const float sv = (s0 + s1) + (s2 + s3);      // full 32-term sum, per lane
        const float s0b = bcast0(sv);                // lane 0 holds j=0 -> s_0
        const float r = __builtin_amdgcn_rcpf(s0b);
        const float pn = sv * r * Fv;
        if (tid == 0) s0_sh[t] = (mc > 0) ? sv : 1.0f;  // off-chain record
        if (tid < 32 && mc > 0) p = pn;
      }
      if (c < 7) {  // transform next chunk to F factors
#pragma unroll
        for (int i = 0; i < 32; ++i) {
          const float b0 = __uint_as_float(__builtin_amdgcn_readfirstlane(__float_as_uint(pre[i])));
          const float b1 = __uint_as_float(__builtin_amdgcn_readlane(__float_as_uint(pre[i]), 32));
          const float base = (tid < 32) ? b0 : b1;
          Lsh[(c & 1) ^ 1][i * 64 + tid] = __expf(pre[i] - base);
        }
      }
    }
    // reconstruct m_T = m0 + sum_{t>=1, masked}(log s0_t + lc_t[0])
    float lsum = 0.f, csum = 0.f;
#pragma unroll
    for (int kk = 0; kk < 8; ++kk) {
      const int t = tid + kk * 64;
      if (t >= 1) {
        lsum += __logf(s0_sh[t]);  // s0_sh[t]=1 when masked-out -> log 0
        if (mk_sh[t] > 0) csum += L[(size_t)t * C_];
      }
    }
#pragma unroll
    for (int d = 32; d; d >>= 1) { lsum += __shfl_xor(lsum, d); csum += __shfl_xor(csum, d); }
    const float mT = m0 + lsum + csum;
    float val = (tid < 32) ? (mT + __logf(p) + et[j]) : NEG_INF;
    float mm = val;
#pragma unroll
    for (int d = 32; d; d >>= 1) mm = fmaxf(mm, __shfl_xor(mm, d));
    float ee = __expf(val - mm);
#pragma unroll
    for (int d = 32; d; d >>= 1) ee += __shfl_xor(ee, d);
    const float logZ = mm + __logf(ee);
    float sc = 0.f, msf = 0.f;
#pragma unroll
    for (int kk = 0; kk < 8; ++kk) {
      const int t = tid + kk * 64;
      const float mf = (float)mk_sh[t];
      const int tg = tgt[b * T_ + t];
      msf += mf;
      float contrib = 0.f;
      if (t >= 1) contrib += trans[tgt[b * T_ + t - 1] * C_ + tg];
      if (t <= T_ - 2) contrib += L[t * C_ + tg];
      sc = fmaf(mf, contrib, sc);
    }
#pragma unroll
    for (int d = 32; d; d >>= 1) { sc += __shfl_xor(sc, d); msf += __shfl_xor(msf, d); }
    if (tid == 0) {
      int last_idx = (int)msf - 1;
      if (last_idx < 0) last_idx = 0;
      const int lt = tgt[b * T_ + last_idx];
      float s = sc + st[tgt[b * T_]] + et[lt];
      s = fmaf((float)mk_sh[T_ - 1], L[(T_ - 1) * C_ + lt], s);
      wsp[b] = logZ;
      wsp[64 + b] = s;
      wsp[128 + b] = msf;
    }
  } else {
    // ================= Viterbi (f32, np-f32-bit-replicating) =================
    float TT[32];
#pragma unroll
    for (int i = 0; i < 32; ++i) TT[i] = trans[i * C_ + j];
#pragma unroll
    for (int i = 0; i < 32; ++i) Lsh[0][i * 64 + tid] = pre[i];  // raw chunk 0
    float dj = st[j] + Lsh[0][j];
    if (tid < 32) f_sh[j] = dj;
    for (int c = 0; c < 8; ++c) {
      if (c < 7) {
#pragma unroll
        for (int i = 0; i < 32; ++i) pre[i] = L[(c + 1) * 2048 + i * 64 + tid];
      }
      const float* Ls = Lsh[c & 1];
      const int tlo = c ? c * 64 : 1;
      const int thi = c * 64 + 64;
      for (int t = tlo; t < thi; ++t) {
        const float lc = Ls[(t - c * 64) * C_ + j];
        const int mc = mk_sh[t];
        // candidates: plain f32 add dd[i]+TT[i] (NOT fma) — matches np rounding
        float cv[32];
#pragma unroll
        for (int i = 0; i < 8; ++i) {
          float4 q = *(const float4*)&f_sh[i * 4];
          cv[i * 4 + 0] = q.x + TT[i * 4 + 0];
          cv[i * 4 + 1] = q.y + TT[i * 4 + 1];
          cv[i * 4 + 2] = q.z + TT[i * 4 + 2];
          cv[i * 4 + 3] = q.w + TT[i * 4 + 3];
        }
        // 5-level tree; left child index < right child index at every node,
        // strict 'right > left' => exact np.argmax first-index tie-break.
        float tv[16]; int ti[16];
#pragma unroll
        for (int k = 0; k < 16; ++k) {
          const bool g = cv[2 * k + 1] > cv[2 * k];
          tv[k] = g ? cv[2 * k + 1] : cv[2 * k];
          ti[k] = g ? 2 * k + 1 : 2 * k;
        }
#pragma unroll
        for (int k = 0; k < 8; ++k) {
          const bool g = tv[2 * k + 1] > tv[2 * k];
          tv[k] = g ? tv[2 * k + 1] : tv[2 * k];
          ti[k] = g ? ti[2 * k + 1] : ti[2 * k];
        }
#pragma unroll
        for (int k = 0; k < 4; ++k) {
          const bool g = tv[2 * k + 1] > tv[2 * k];
          tv[k] = g ? tv[2 * k + 1] : tv[2 * k];
          ti[k] = g ? ti[2 * k + 1] : ti[2 * k];
        }
#pragma unroll
        for (int k = 0; k < 2; ++k) {
          const bool g = tv[2 * k + 1] > tv[2 * k];
          tv[k] = g ? tv[2 * k + 1] : tv[2 * k];
          ti[k] = g ? ti[2 * k + 1] : ti[2 * k];
        }
        const bool gf = tv[1] > tv[0];
        const float bestv = gf ? tv[1] : tv[0];
        const int besti = gf ? ti[1] : ti[0];
        if (tid < 32) {
          int bpv = j;
          if (mc > 0) { dj = bestv + lc; bpv = besti; }  // f32 add: matches np best+lt
          bp[(t - 1) * C_ + j] = (unsigned char)bpv;
          f_sh[j] = dj;
        }
      }
      if (c < 7) {
#pragma unroll
        for (int i = 0; i < 32; ++i) Lsh[(c & 1) ^ 1][i * 64 + tid] = pre[i];
      }
    }
    // final argmax (first-index tie-break) + path score — f32 elementwise
    float fv = (tid < 32) ? (dj + et[j]) : NEG_INF;
    int fi = (tid < 32) ? j : 64;
#pragma unroll
    for (int d = 32; d; d >>= 1) {
      const float ov = __shfl_xor(fv, d);
      const int oi = __shfl_xor(fi, d);
      if (ov > fv || (ov == fv && oi < fi)) { fv = ov; fi = oi; }
    }
    const int last_tag = fi;
    if (tid == 0) path_out[b] = fv;
    // ---- backtrace: 8-step jump maps ----
    int cur[32];
#pragma unroll
    for (int e = 0; e < 32; ++e) cur[e] = (tid + 64 * e) & 31;
#pragma unroll
    for (int s = 0; s < 8; ++s) {
#pragma unroll
      for (int e = 0; e < 32; ++e) {
        const int m = (tid + 64 * e) >> 5;
        const int r = 8 * m + 7 - s;
        if (r <= T_ - 2) cur[e] = bp[r * C_ + cur[e]];
      }
    }
#pragma unroll
    for (int e = 0; e < 32; ++e) c8[tid + 64 * e] = (unsigned char)cur[e];
    if (tid == 0) {
      int c = last_tag;
      tagb[T_ - 1] = (unsigned char)c;
      for (int m = 63; m >= 0; --m) { c = c8[m * C_ + c]; btag[m] = c; }  // btag[m]=tag_{8m}
    }
    {
      const int m = tid;
      const int rhi = (m == 63) ? (T_ - 2) : (8 * m + 7);
      int c = (m == 63) ? last_tag : btag[m + 1];
#pragma unroll
      for (int s = 0; s < 7; ++s) {
        const int r = rhi - s;
        if (r >= 8 * m + 1) { c = bp[r * C_ + c]; tagb[r] = (unsigned char)c; }
      }
      tagb[8 * m] = (unsigned char)btag[m];
    }
#pragma unroll
    for (int kk = 0; kk < 8; ++kk) {
      const int t = tid + kk * 64;
      tags_out[b * T_ + t] = (float)tagb[t];
    }
  }
}

// ---------------- loss reduction ----------------
__global__ __launch_bounds__(64) void k_loss(const float* __restrict__ wsp, float* __restrict__ out0) {
  const int tid = threadIdx.x;
  float d = wsp[64 + tid] - wsp[tid];
  float m = wsp[128 + tid];
#pragma unroll
  for (int s = 32; s; s >>= 1) { d += __shfl_xor(d, s); m += __shfl_xor(m, s); }
  if (tid == 0) out0[0] = -d / m;
}

extern "C" void kernel_launch(void* const* d_in, const int* in_sizes, int n_in,
                              void* d_out, int out_size, void* d_ws, size_t ws_size,
                              hipStream_t stream) {
  (void)in_sizes; (void)n_in; (void)out_size; (void)ws_size;
  const float* vec  = (const float*)d_in[0];
  const int* mask   = (const int*)d_in[1];
  const int* tgt    = (const int*)d_in[2];
  const float* W    = (const float*)d_in[3];
  const float* bias = (const float*)d_in[4];
  const float* tr   = (const float*)d_in[5];
  const float* st   = (const float*)d_in[6];
  const float* et   = (const float*)d_in[7];
  float* out = (float*)d_out;
  float* logits = out + 1;
  float* tags = out + 1 + (size_t)B_ * T_ * C_;
  float* path = tags + (size_t)B_ * T_;
  float* wsp = (float*)d_ws;  // [0,64): logZ  [64,128): score  [128,192): mask-sum

  hipLaunchKernelGGL(k_logits, dim3(256), dim3(256), 0, stream, vec, W, bias, logits);
  hipLaunchKernelGGL(k_crf, dim3(128), dim3(64), 0, stream, logits, mask, tgt, tr, st, et, wsp, tags, path);
  hipLaunchKernelGGL(k_loss, dim3(1), dim3(64), 0, stream, wsp, out);
}

// Round 4
// 644.040 us; speedup vs baseline: 2.9496x; 2.9496x over previous
//
#include <hip/hip_runtime.h>

#define B_ 64
#define T_ 512
#define D_ 1024
#define C_ 32
#define CHUNK 16              // rows staged per chunk (pre[8] per lane)
#define NCHUNK (T_ / CHUNK)   // 32
#define NEG_INF (-1e30f)

__device__ __forceinline__ float bcast0(float v) {
  return __uint_as_float(__builtin_amdgcn_readfirstlane(__float_as_uint(v)));
}

// ---------------- logits = vectors @ W^T + b (f32, sequential-k fma chain) ----------------
// grid 256, block 256. Block tile: 128 rows x 32 cols. Thread: 4 rows (stride 32) x 4 cols (stride 8).
__global__ __launch_bounds__(256) void k_logits(const float* __restrict__ vec,
                                                const float* __restrict__ W,
                                                const float* __restrict__ bias,
                                                float* __restrict__ out) {
  const int tid = threadIdx.x;
  const int cg = tid & 7;   // col base 0..7  (cols cg + 8*cc)
  const int rg = tid >> 3;  // 0..31          (rows r0 + rg + 32*rr)
  const int r0 = blockIdx.x * 128;
  float acc[4][4];
#pragma unroll
  for (int a = 0; a < 4; ++a)
#pragma unroll
    for (int bb = 0; bb < 4; ++bb) acc[a][bb] = 0.f;
  const float* vb = vec + (size_t)(r0 + rg) * D_;
  const float* wb = W + (size_t)cg * D_;
#pragma unroll 4
  for (int k = 0; k < D_; k += 4) {
    float4 v[4], w[4];
#pragma unroll
    for (int rr = 0; rr < 4; ++rr) v[rr] = *(const float4*)(vb + (size_t)rr * 32 * D_ + k);
#pragma unroll
    for (int cc = 0; cc < 4; ++cc) w[cc] = *(const float4*)(wb + (size_t)cc * 8 * D_ + k);
#pragma unroll
    for (int rr = 0; rr < 4; ++rr)
#pragma unroll
      for (int cc = 0; cc < 4; ++cc) {
        acc[rr][cc] = fmaf(v[rr].x, w[cc].x, acc[rr][cc]);
        acc[rr][cc] = fmaf(v[rr].y, w[cc].y, acc[rr][cc]);
        acc[rr][cc] = fmaf(v[rr].z, w[cc].z, acc[rr][cc]);
        acc[rr][cc] = fmaf(v[rr].w, w[cc].w, acc[rr][cc]);
      }
  }
#pragma unroll
  for (int rr = 0; rr < 4; ++rr) {
    const size_t row = (size_t)(r0 + rg + rr * 32);
#pragma unroll
    for (int cc = 0; cc < 4; ++cc) {
      const int c = cg + cc * 8;
      out[row * C_ + c] = acc[rr][cc] + bias[c];  // b32 store: out base only 4B-aligned
    }
  }
}

// ---------------- CRF: forward(+score) and Viterbi(+backtrace) ----------------
// grid 128 x 64 threads (one wave64 per block -> LDS in-order, no barriers).
// blocks 0..63: forward in SCALED-PROBABILITY space (exp/log-free chain); each
//   lane computes the FULL 32-term fma sum streamed group-by-group (no av[32]
//   materialization). Numerics validated R2/R3 (loss passed).
// blocks 64..127: f32 Viterbi; each lane computes the FULL 32-candidate argmax
//   via streamed groups-of-4 + 3-level tree. Left child always lower index +
//   strict 'right > left' == np.argmax first-index ties (validated R3: tags
//   bit-exact). R3's 7.7x regression was register spill (cv[32]+tv+ti+pre[32]
//   +TT[32] > VGPR budget -> per-step scratch traffic); this version's peak
//   live set is ~70 regs: TT[32]/ET[32] + pre[8] (16-row chunks) + gv/gi[8].
__global__ __launch_bounds__(64) void k_crf(const float* __restrict__ lg,
                                            const int* __restrict__ mask,
                                            const int* __restrict__ tgt,
                                            const float* __restrict__ trans,
                                            const float* __restrict__ st,
                                            const float* __restrict__ et,
                                            float* __restrict__ wsp,
                                            float* __restrict__ tags_out,
                                            float* __restrict__ path_out) {
  __shared__ __align__(16) float a_sh[C_];
  __shared__ __align__(16) float f_sh[C_];
  __shared__ __align__(16) float Lsh[2][CHUNK * C_];  // role0: exp(lc-lc0); role1: raw logits
  __shared__ float s0_sh[T_];
  __shared__ int mk_sh[T_];
  __shared__ unsigned char bp[(T_ - 1) * C_];
  __shared__ unsigned char tagb[T_];
  __shared__ unsigned char c8[64 * C_];
  __shared__ int btag[64];

  const int tid = threadIdx.x;
  const int b = blockIdx.x & 63;
  const int role = blockIdx.x >> 6;
  const int j = tid & 31;
  const int h = tid >> 5;
  const float* L = lg + (size_t)b * T_ * C_;
  const int* mk = mask + b * T_;

  // ---- load chunk 0 (rows 0..15) to regs + full mask into LDS ----
  float pre[8];
#pragma unroll
  for (int i = 0; i < 8; ++i) pre[i] = L[i * 64 + tid];
  {
    int4 m0 = *(const int4*)(mk + tid * 4);
    int4 m1 = *(const int4*)(mk + 256 + tid * 4);
    *(int4*)&mk_sh[tid * 4] = m0;
    *(int4*)&mk_sh[256 + tid * 4] = m1;
  }

  if (role == 0) {
    // ================= forward (scaled-prob space) + score =================
    float ET[32];
#pragma unroll
    for (int i = 0; i < 32; ++i) ET[i] = __expf(trans[i * C_ + j]);
    const float a0j = st[j] + L[j];
    const float m0 = bcast0(a0j);
    float p = (tid < 32) ? __expf(a0j - m0) : 0.f;
    // transform chunk 0 -> F factors. pre[i]: lanes 0-31 hold row 2i, lanes
    // 32-63 hold row 2i+1; col-0 base is lane 0 / lane 32 respectively.
#pragma unroll
    for (int i = 0; i < 8; ++i) {
      const float b0 = __uint_as_float(__builtin_amdgcn_readfirstlane(__float_as_uint(pre[i])));
      const float b1 = __uint_as_float(__builtin_amdgcn_readlane(__float_as_uint(pre[i]), 32));
      const float base = (tid < 32) ? b0 : b1;
      Lsh[0][i * 64 + tid] = __expf(pre[i] - base);
    }
    for (int c = 0; c < NCHUNK; ++c) {
      if (c < NCHUNK - 1) {  // issue next chunk's global loads before compute
#pragma unroll
        for (int i = 0; i < 8; ++i) pre[i] = L[(c + 1) * (CHUNK * C_) + i * 64 + tid];
      }
      const float* Fs = Lsh[c & 1];
      const int tlo = c ? c * CHUNK : 1;
      const int thi = c * CHUNK + CHUNK;
      for (int t = tlo; t < thi; ++t) {
        const float Fv = Fs[(t - c * CHUNK) * C_ + j];  // off-chain
        const int mc = mk_sh[t];                        // off-chain
        if (tid < 32) a_sh[j] = p;                      // chain: LDS round trip
        float4 q = *(const float4*)&a_sh[0];
        float s0 = q.x * ET[0], s1 = q.y * ET[1], s2 = q.z * ET[2], s3 = q.w * ET[3];
#pragma unroll
        for (int g = 1; g < 8; ++g) {
          q = *(const float4*)&a_sh[g * 4];
          s0 = fmaf(q.x, ET[4 * g + 0], s0);
          s1 = fmaf(q.y, ET[4 * g + 1], s1);
          s2 = fmaf(q.z, ET[4 * g + 2], s2);
          s3 = fmaf(q.w, ET[4 * g + 3], s3);
        }
        const float sv = (s0 + s1) + (s2 + s3);  // full 32-term sum, per lane
        const float s0b = bcast0(sv);            // lane 0 holds j=0 -> s_0
        const float r = __builtin_amdgcn_rcpf(s0b);
        const float pn = sv * r * Fv;
        if (tid == 0) s0_sh[t] = (mc > 0) ? sv : 1.0f;  // off-chain record
        if (tid < 32 && mc > 0) p = pn;
      }
      if (c < NCHUNK - 1) {  // transform next chunk to F factors
#pragma unroll
        for (int i = 0; i < 8; ++i) {
          const float b0 = __uint_as_float(__builtin_amdgcn_readfirstlane(__float_as_uint(pre[i])));
          const float b1 = __uint_as_float(__builtin_amdgcn_readlane(__float_as_uint(pre[i]), 32));
          const float base = (tid < 32) ? b0 : b1;
          Lsh[(c & 1) ^ 1][i * 64 + tid] = __expf(pre[i] - base);
        }
      }
    }
    // reconstruct m_T = m0 + sum_{t>=1, masked}(log s0_t + lc_t[0])
    float lsum = 0.f, csum = 0.f;
#pragma unroll
    for (int kk = 0; kk < 8; ++kk) {
      const int t = tid + kk * 64;
      if (t >= 1) {
        lsum += __logf(s0_sh[t]);  // s0_sh[t]=1 when masked-out -> log 0
        if (mk_sh[t] > 0) csum += L[(size_t)t * C_];
      }
    }
#pragma unroll
    for (int d = 32; d; d >>= 1) { lsum += __shfl_xor(lsum, d); csum += __shfl_xor(csum, d); }
    const float mT = m0 + lsum + csum;
    float val = (tid < 32) ? (mT + __logf(p) + et[j]) : NEG_INF;
    float mm = val;
#pragma unroll
    for (int d = 32; d; d >>= 1) mm = fmaxf(mm, __shfl_xor(mm, d));
    float ee = __expf(val - mm);
#pragma unroll
    for (int d = 32; d; d >>= 1) ee += __shfl_xor(ee, d);
    const float logZ = mm + __logf(ee);
    float sc = 0.f, msf = 0.f;
#pragma unroll
    for (int kk = 0; kk < 8; ++kk) {
      const int t = tid + kk * 64;
      const float mf = (float)mk_sh[t];
      const int tg = tgt[b * T_ + t];
      msf += mf;
      float contrib = 0.f;
      if (t >= 1) contrib += trans[tgt[b * T_ + t - 1] * C_ + tg];
      if (t <= T_ - 2) contrib += L[t * C_ + tg];
      sc = fmaf(mf, contrib, sc);
    }
#pragma unroll
    for (int d = 32; d; d >>= 1) { sc += __shfl_xor(sc, d); msf += __shfl_xor(msf, d); }
    if (tid == 0) {
      int last_idx = (int)msf - 1;
      if (last_idx < 0) last_idx = 0;
      const int lt = tgt[b * T_ + last_idx];
      float s = sc + st[tgt[b * T_]] + et[lt];
      s = fmaf((float)mk_sh[T_ - 1], L[(T_ - 1) * C_ + lt], s);
      wsp[b] = logZ;
      wsp[64 + b] = s;
      wsp[128 + b] = msf;
    }
  } else {
    // ================= Viterbi (f32, np-f32-bit-replicating) =================
    float TT[32];
#pragma unroll
    for (int i = 0; i < 32; ++i) TT[i] = trans[i * C_ + j];
#pragma unroll
    for (int i = 0; i < 8; ++i) Lsh[0][i * 64 + tid] = pre[i];  // raw chunk 0
    float dj = st[j] + Lsh[0][j];
    if (tid < 32) f_sh[j] = dj;
    for (int c = 0; c < NCHUNK; ++c) {
      if (c < NCHUNK - 1) {
#pragma unroll
        for (int i = 0; i < 8; ++i) pre[i] = L[(c + 1) * (CHUNK * C_) + i * 64 + tid];
      }
      const float* Ls = Lsh[c & 1];
      const int tlo = c ? c * CHUNK : 1;
      const int thi = c * CHUNK + CHUNK;
      for (int t = tlo; t < thi; ++t) {
        const float lc = Ls[(t - c * CHUNK) * C_ + j];
        const int mc = mk_sh[t];
        // streamed argmax over 32 candidates dd[i]+TT[i] (plain f32 add, NOT
        // fma — matches np rounding). Groups of 4 reduced on the fly; only
        // gv[8]/gi[8] live. Left-lower-index + strict '>' at every node ==
        // exact np.argmax first-index tie-break.
        float gv[8]; int gi[8];
#pragma unroll
        for (int g = 0; g < 8; ++g) {
          float4 q = *(const float4*)&f_sh[g * 4];
          const float c0 = q.x + TT[4 * g + 0];
          const float c1 = q.y + TT[4 * g + 1];
          const float c2 = q.z + TT[4 * g + 2];
          const float c3 = q.w + TT[4 * g + 3];
          const bool b01 = c1 > c0;
          const float v01 = b01 ? c1 : c0; const int i01 = 4 * g + (b01 ? 1 : 0);
          const bool b23 = c3 > c2;
          const float v23 = b23 ? c3 : c2; const int i23 = 4 * g + 2 + (b23 ? 1 : 0);
          const bool bg = v23 > v01;
          gv[g] = bg ? v23 : v01; gi[g] = bg ? i23 : i01;
        }
        float hv[4]; int hi[4];
#pragma unroll
        for (int k = 0; k < 4; ++k) {
          const bool g = gv[2 * k + 1] > gv[2 * k];
          hv[k] = g ? gv[2 * k + 1] : gv[2 * k];
          hi[k] = g ? gi[2 * k + 1] : gi[2 * k];
        }
        const bool ga = hv[1] > hv[0];
        const float va = ga ? hv[1] : hv[0]; const int ia = ga ? hi[1] : hi[0];
        const bool gb = hv[3] > hv[2];
        const float vb = gb ? hv[3] : hv[2]; const int ib = gb ? hi[3] : hi[2];
        const bool gf = vb > va;
        const float bestv = gf ? vb : va; const int besti = gf ? ib : ia;
        if (tid < 32) {
          int bpv = j;
          if (mc > 0) { dj = bestv + lc; bpv = besti; }  // f32 add: matches np best+lt
          bp[(t - 1) * C_ + j] = (unsigned char)bpv;
          f_sh[j] = dj;
        }
      }
      if (c < NCHUNK - 1) {
#pragma unroll
        for (int i = 0; i < 8; ++i) Lsh[(c & 1) ^ 1][i * 64 + tid] = pre[i];
      }
    }
    // final argmax (first-index tie-break) + path score — f32 elementwise
    float fv = (tid < 32) ? (dj + et[j]) : NEG_INF;
    int fi = (tid < 32) ? j : 64;
#pragma unroll
    for (int d = 32; d; d >>= 1) {
      const float ov = __shfl_xor(fv, d);
      const int oi = __shfl_xor(fi, d);
      if (ov > fv || (ov == fv && oi < fi)) { fv = ov; fi = oi; }
    }
    const int last_tag = fi;
    if (tid == 0) path_out[b] = fv;
    // ---- backtrace: 8-step jump maps ----
    int cur[32];
#pragma unroll
    for (int e = 0; e < 32; ++e) cur[e] = (tid + 64 * e) & 31;
#pragma unroll
    for (int s = 0; s < 8; ++s) {
#pragma unroll
      for (int e = 0; e < 32; ++e) {
        const int m = (tid + 64 * e) >> 5;
        const int r = 8 * m + 7 - s;
        if (r <= T_ - 2) cur[e] = bp[r * C_ + cur[e]];
      }
    }
#pragma unroll
    for (int e = 0; e < 32; ++e) c8[tid + 64 * e] = (unsigned char)cur[e];
    if (tid == 0) {
      int c = last_tag;
      tagb[T_ - 1] = (unsigned char)c;
      for (int m = 63; m >= 0; --m) { c = c8[m * C_ + c]; btag[m] = c; }  // btag[m]=tag_{8m}
    }
    {
      const int m = tid;
      const int rhi = (m == 63) ? (T_ - 2) : (8 * m + 7);
      int c = (m == 63) ? last_tag : btag[m + 1];
#pragma unroll
      for (int s = 0; s < 7; ++s) {
        const int r = rhi - s;
        if (r >= 8 * m + 1) { c = bp[r * C_ + c]; tagb[r] = (unsigned char)c; }
      }
      tagb[8 * m] = (unsigned char)btag[m];
    }
#pragma unroll
    for (int kk = 0; kk < 8; ++kk) {
      const int t = tid + kk * 64;
      tags_out[b * T_ + t] = (float)tagb[t];
    }
  }
}

// ---------------- loss reduction ----------------
__global__ __launch_bounds__(64) void k_loss(const float* __restrict__ wsp, float* __restrict__ out0) {
  const int tid = threadIdx.x;
  float d = wsp[64 + tid] - wsp[tid];
  float m = wsp[128 + tid];
#pragma unroll
  for (int s = 32; s; s >>= 1) { d += __shfl_xor(d, s); m += __shfl_xor(m, s); }
  if (tid == 0) out0[0] = -d / m;
}

extern "C" void kernel_launch(void* const* d_in, const int* in_sizes, int n_in,
                              void* d_out, int out_size, void* d_ws, size_t ws_size,
                              hipStream_t stream) {
  (void)in_sizes; (void)n_in; (void)out_size; (void)ws_size;
  const float* vec  = (const float*)d_in[0];
  const int* mask   = (const int*)d_in[1];
  const int* tgt    = (const int*)d_in[2];
  const float* W    = (const float*)d_in[3];
  const float* bias = (const float*)d_in[4];
  const float* tr   = (const float*)d_in[5];
  const float* st   = (const float*)d_in[6];
  const float* et   = (const float*)d_in[7];
  float* out = (float*)d_out;
  float* logits = out + 1;
  float* tags = out + 1 + (size_t)B_ * T_ * C_;
  float* path = tags + (size_t)B_ * T_;
  float* wsp = (float*)d_ws;  // [0,64): logZ  [64,128): score  [128,192): mask-sum

  hipLaunchKernelGGL(k_logits, dim3(256), dim3(256), 0, stream, vec, W, bias, logits);
  hipLaunchKernelGGL(k_crf, dim3(128), dim3(64), 0, stream, logits, mask, tgt, tr, st, et, wsp, tags, path);
  hipLaunchKernelGGL(k_loss, dim3(1), dim3(64), 0, stream, wsp, out);
}

// Round 5
// 547.784 us; speedup vs baseline: 3.4679x; 1.1757x over previous
//
#include <hip/hip_runtime.h>

#define B_ 64
#define T_ 512
#define D_ 1024
#define C_ 32
#define CHUNK 16              // logits rows staged per chunk (pre[8] per lane)
#define NCHUNK (T_ / CHUNK)   // 32
#define NEG_INF (-1e30f)

__device__ __forceinline__ float bcast0(float v) {
  return __uint_as_float(__builtin_amdgcn_readfirstlane(__float_as_uint(v)));
}
// exact cross-lane read (compiler builtin: hazards modeled, uniform result -> SGPR)
__device__ __forceinline__ float rlane(float v, int l) {
  return __uint_as_float(__builtin_amdgcn_readlane(__float_as_uint(v), l));
}

// ---------------- logits = vectors @ W^T + b (f32, sequential-k fma chain) ----------------
// grid 256, block 256. Block tile: 128 rows x 32 cols. Thread: 4 rows (stride 32) x 4 cols (stride 8).
__global__ __launch_bounds__(256) void k_logits(const float* __restrict__ vec,
                                                const float* __restrict__ W,
                                                const float* __restrict__ bias,
                                                float* __restrict__ out) {
  const int tid = threadIdx.x;
  const int cg = tid & 7;   // col base 0..7  (cols cg + 8*cc)
  const int rg = tid >> 3;  // 0..31          (rows r0 + rg + 32*rr)
  const int r0 = blockIdx.x * 128;
  float acc[4][4];
#pragma unroll
  for (int a = 0; a < 4; ++a)
#pragma unroll
    for (int bb = 0; bb < 4; ++bb) acc[a][bb] = 0.f;
  const float* vb = vec + (size_t)(r0 + rg) * D_;
  const float* wb = W + (size_t)cg * D_;
#pragma unroll 4
  for (int k = 0; k < D_; k += 4) {
    float4 v[4], w[4];
#pragma unroll
    for (int rr = 0; rr < 4; ++rr) v[rr] = *(const float4*)(vb + (size_t)rr * 32 * D_ + k);
#pragma unroll
    for (int cc = 0; cc < 4; ++cc) w[cc] = *(const float4*)(wb + (size_t)cc * 8 * D_ + k);
#pragma unroll
    for (int rr = 0; rr < 4; ++rr)
#pragma unroll
      for (int cc = 0; cc < 4; ++cc) {
        acc[rr][cc] = fmaf(v[rr].x, w[cc].x, acc[rr][cc]);
        acc[rr][cc] = fmaf(v[rr].y, w[cc].y, acc[rr][cc]);
        acc[rr][cc] = fmaf(v[rr].z, w[cc].z, acc[rr][cc]);
        acc[rr][cc] = fmaf(v[rr].w, w[cc].w, acc[rr][cc]);
      }
  }
#pragma unroll
  for (int rr = 0; rr < 4; ++rr) {
    const size_t row = (size_t)(r0 + rg + rr * 32);
#pragma unroll
    for (int cc = 0; cc < 4; ++cc) {
      const int c = cg + cc * 8;
      out[row * C_ + c] = acc[rr][cc] + bias[c];  // b32 store: out base only 4B-aligned
    }
  }
}

// ---------------- CRF: forward(+score) and Viterbi(+backtrace) ----------------
// grid 128 x 64 threads (one wave64 per block -> LDS in-order, no barriers).
// R5 restructure: the serial t-loop is issue/latency-bound at 1 wave/SIMD
// (~9cy per VALU instr on the chain, measured across R1/R4). So:
//  (a) DP state lives in SGPRs via 32x v_readlane broadcast after each step —
//      no LDS round-trip on the chain (bit-exact data movement, builtin).
//  (b) Viterbi serial loop computes VALUES ONLY (32 add + 15 fmax + update);
//      delta vectors are stored to a 256-row LDS ring (off-chain writes) and
//      backpointers are recomputed IN PARALLEL afterwards (2 t per wave-iter,
//      descending '>=' scan == np.argmax first-index semantics, the R3/R4-
//      validated form). Ring => two passes: phase2a after step 255, 2b at end.
//  (c) forward keeps R4's validated scaled-prob arithmetic (identical
//      association/rounding); s0_sh stored from the uniform readfirstlane
//      value (same bits as R4's lane-0 store).
__global__ __launch_bounds__(64) void k_crf(const float* __restrict__ lg,
                                            const int* __restrict__ mask,
                                            const int* __restrict__ tgt,
                                            const float* __restrict__ trans,
                                            const float* __restrict__ st,
                                            const float* __restrict__ et,
                                            float* __restrict__ wsp,
                                            float* __restrict__ tags_out,
                                            float* __restrict__ path_out) {
  __shared__ __align__(16) float dsh[256 * C_];       // delta ring (role1), 32KB
  __shared__ __align__(16) float Lsh[2][CHUNK * C_];  // staged logits chunks, 4KB
  __shared__ float s0_sh[T_];                          // role0 scale record
  __shared__ int mk_sh[T_];
  __shared__ unsigned char bp[(T_ - 1) * C_];
  __shared__ unsigned char tagb[T_];
  __shared__ unsigned char c8[64 * C_];
  __shared__ int btag[64];

  const int tid = threadIdx.x;
  const int b = blockIdx.x & 63;
  const int role = blockIdx.x >> 6;
  const int j = tid & 31;
  const int h = tid >> 5;
  const float* L = lg + (size_t)b * T_ * C_;
  const int* mk = mask + b * T_;

  // ---- load chunk 0 (rows 0..15) to regs + full mask into LDS ----
  float pre[8];
#pragma unroll
  for (int i = 0; i < 8; ++i) pre[i] = L[i * 64 + tid];
  {
    int4 m0 = *(const int4*)(mk + tid * 4);
    int4 m1 = *(const int4*)(mk + 256 + tid * 4);
    *(int4*)&mk_sh[tid * 4] = m0;
    *(int4*)&mk_sh[256 + tid * 4] = m1;
  }

  if (role == 0) {
    // ================= forward (scaled-prob space, SGPR state) + score ======
    float ET[32];
#pragma unroll
    for (int i = 0; i < 32; ++i) ET[i] = __expf(trans[i * C_ + j]);
    const float a0j = st[j] + L[j];
    const float m0 = bcast0(a0j);
    float vp = __expf(a0j - m0);  // per-lane p (lanes 32-63 mirror lanes 0-31)
    float sp[32];
#pragma unroll
    for (int k = 0; k < 32; ++k) sp[k] = rlane(vp, k);
    // chunk 0 -> F factors. pre[i]: lanes 0-31 = row 2i, lanes 32-63 = row
    // 2i+1; col-0 base is lane 0 / lane 32 respectively.
#pragma unroll
    for (int i = 0; i < 8; ++i) {
      const float b0v = rlane(pre[i], 0);
      const float b1v = rlane(pre[i], 32);
      const float base = (tid < 32) ? b0v : b1v;
      Lsh[0][i * 64 + tid] = __expf(pre[i] - base);
    }
    for (int c = 0; c < NCHUNK; ++c) {
      if (c < NCHUNK - 1) {
#pragma unroll
        for (int i = 0; i < 8; ++i) pre[i] = L[(c + 1) * (CHUNK * C_) + i * 64 + tid];
      }
      const float* Fs = Lsh[c & 1];
      const int tlo = c ? c * CHUNK : 1;
      const int thi = c * CHUNK + CHUNK;
      for (int t = tlo; t < thi; ++t) {
        const float Fv = Fs[(t - c * CHUNK) * C_ + j];  // off-chain
        const int mc = mk_sh[t];                        // off-chain
        // full 32-term fma sum, SGPR operands (same association as R4)
        float s0 = sp[0] * ET[0], s1 = sp[1] * ET[1], s2 = sp[2] * ET[2], s3 = sp[3] * ET[3];
#pragma unroll
        for (int g = 1; g < 8; ++g) {
          s0 = fmaf(sp[4 * g + 0], ET[4 * g + 0], s0);
          s1 = fmaf(sp[4 * g + 1], ET[4 * g + 1], s1);
          s2 = fmaf(sp[4 * g + 2], ET[4 * g + 2], s2);
          s3 = fmaf(sp[4 * g + 3], ET[4 * g + 3], s3);
        }
        const float sv = (s0 + s1) + (s2 + s3);
        const float s0b = bcast0(sv);            // lane 0 holds j=0 -> s_0
        const float r = __builtin_amdgcn_rcpf(s0b);
        const float pn = sv * r * Fv;
        vp = (mc > 0) ? pn : vp;
        s0_sh[t] = (mc > 0) ? s0b : 1.0f;        // uniform value: dup-safe store
#pragma unroll
        for (int k = 0; k < 32; ++k) sp[k] = rlane(vp, k);
      }
      if (c < NCHUNK - 1) {
#pragma unroll
        for (int i = 0; i < 8; ++i) {
          const float b0v = rlane(pre[i], 0);
          const float b1v = rlane(pre[i], 32);
          const float base = (tid < 32) ? b0v : b1v;
          Lsh[(c & 1) ^ 1][i * 64 + tid] = __expf(pre[i] - base);
        }
      }
    }
    // reconstruct m_T = m0 + sum_{t>=1, masked}(log s0_t + lc_t[0])
    float lsum = 0.f, csum = 0.f;
#pragma unroll
    for (int kk = 0; kk < 8; ++kk) {
      const int t = tid + kk * 64;
      if (t >= 1) {
        lsum += __logf(s0_sh[t]);  // s0_sh[t]=1 when masked-out -> log 0
        if (mk_sh[t] > 0) csum += L[(size_t)t * C_];
      }
    }
#pragma unroll
    for (int d = 32; d; d >>= 1) { lsum += __shfl_xor(lsum, d); csum += __shfl_xor(csum, d); }
    const float mT = m0 + lsum + csum;
    float val = (tid < 32) ? (mT + __logf(vp) + et[j]) : NEG_INF;
    float mm = val;
#pragma unroll
    for (int d = 32; d; d >>= 1) mm = fmaxf(mm, __shfl_xor(mm, d));
    float ee = __expf(val - mm);
#pragma unroll
    for (int d = 32; d; d >>= 1) ee += __shfl_xor(ee, d);
    const float logZ = mm + __logf(ee);
    float sc = 0.f, msf = 0.f;
#pragma unroll
    for (int kk = 0; kk < 8; ++kk) {
      const int t = tid + kk * 64;
      const float mf = (float)mk_sh[t];
      const int tg = tgt[b * T_ + t];
      msf += mf;
      float contrib = 0.f;
      if (t >= 1) contrib += trans[tgt[b * T_ + t - 1] * C_ + tg];
      if (t <= T_ - 2) contrib += L[t * C_ + tg];
      sc = fmaf(mf, contrib, sc);
    }
#pragma unroll
    for (int d = 32; d; d >>= 1) { sc += __shfl_xor(sc, d); msf += __shfl_xor(msf, d); }
    if (tid == 0) {
      int last_idx = (int)msf - 1;
      if (last_idx < 0) last_idx = 0;
      const int lt = tgt[b * T_ + last_idx];
      float s = sc + st[tgt[b * T_]] + et[lt];
      s = fmaf((float)mk_sh[T_ - 1], L[(T_ - 1) * C_ + lt], s);
      wsp[b] = logZ;
      wsp[64 + b] = s;
      wsp[128 + b] = msf;
    }
  } else {
    // ================= Viterbi (f32, np-f32-bit-replicating) =================
    float TT[32];
#pragma unroll
    for (int i = 0; i < 32; ++i) TT[i] = trans[i * C_ + j];
#pragma unroll
    for (int i = 0; i < 8; ++i) Lsh[0][i * 64 + tid] = pre[i];  // raw chunk 0
    float vdj = st[j] + L[j];
    float sd[32];
#pragma unroll
    for (int k = 0; k < 32; ++k) sd[k] = rlane(vdj, k);
    dsh[j] = vdj;  // ring row 0 = delta_0 (lanes j and j+32: same addr, same value)

    // parallel bp recompute: 2 t-values per iteration (half-wave each).
    // Descending '>=' scan == np.argmax first-index tie-break (exact values:
    // plain f32 add delta+TT, same bits as the serial loop's candidates).
    auto phase2 = [&](int tb) {
#pragma unroll 2
      for (int it = 0; it < 128; ++it) {
        const int t = tb + 2 * it + h;
        if (t < T_) {
          const float* dr = &dsh[((t - 1) & 255) * C_];
          float best; int idx;
          {
            float4 q = *(const float4*)&dr[28];
            best = q.w + TT[31]; idx = 31;
            float cx = q.z + TT[30]; bool ge = cx >= best; best = ge ? cx : best; idx = ge ? 30 : idx;
            cx = q.y + TT[29]; ge = cx >= best; best = ge ? cx : best; idx = ge ? 29 : idx;
            cx = q.x + TT[28]; ge = cx >= best; best = ge ? cx : best; idx = ge ? 28 : idx;
          }
#pragma unroll
          for (int g = 6; g >= 0; --g) {
            float4 q = *(const float4*)&dr[4 * g];
            float cx = q.w + TT[4 * g + 3]; bool ge = cx >= best; best = ge ? cx : best; idx = ge ? 4 * g + 3 : idx;
            cx = q.z + TT[4 * g + 2]; ge = cx >= best; best = ge ? cx : best; idx = ge ? 4 * g + 2 : idx;
            cx = q.y + TT[4 * g + 1]; ge = cx >= best; best = ge ? cx : best; idx = ge ? 4 * g + 1 : idx;
            cx = q.x + TT[4 * g + 0]; ge = cx >= best; best = ge ? cx : best; idx = ge ? 4 * g + 0 : idx;
          }
          const int bpv = (mk_sh[t] > 0) ? idx : j;
          bp[(t - 1) * C_ + j] = (unsigned char)bpv;
        }
      }
    };

    for (int c = 0; c < NCHUNK; ++c) {
      if (c < NCHUNK - 1) {
#pragma unroll
        for (int i = 0; i < 8; ++i) pre[i] = L[(c + 1) * (CHUNK * C_) + i * 64 + tid];
      }
      const float* Ls = Lsh[c & 1];
      const int tlo = c ? c * CHUNK : 1;
      const int thi = c * CHUNK + CHUNK;
      for (int t = tlo; t < thi; ++t) {
        const float lc = Ls[(t - c * CHUNK) * C_ + j];  // off-chain
        const int mc = mk_sh[t];                        // off-chain
        // VALUES ONLY: 32 plain f32 adds (np rounding) + exact max tree.
        float gm[8];
#pragma unroll
        for (int g = 0; g < 8; ++g) {
          const float c0 = sd[4 * g + 0] + TT[4 * g + 0];
          const float c1 = sd[4 * g + 1] + TT[4 * g + 1];
          const float c2 = sd[4 * g + 2] + TT[4 * g + 2];
          const float c3 = sd[4 * g + 3] + TT[4 * g + 3];
          gm[g] = fmaxf(fmaxf(c0, c1), fmaxf(c2, c3));
        }
        const float m01 = fmaxf(gm[0], gm[1]), m23 = fmaxf(gm[2], gm[3]);
        const float m45 = fmaxf(gm[4], gm[5]), m67 = fmaxf(gm[6], gm[7]);
        const float bestv = fmaxf(fmaxf(m01, m23), fmaxf(m45, m67));
        vdj = (mc > 0) ? (bestv + lc) : vdj;  // f32 add: matches np best+lt
        dsh[(t & 255) * C_ + j] = vdj;        // off-chain ring store (dup-safe)
#pragma unroll
        for (int k = 0; k < 32; ++k) sd[k] = rlane(vdj, k);
      }
      if (c < NCHUNK - 1) {
#pragma unroll
        for (int i = 0; i < 8; ++i) Lsh[(c & 1) ^ 1][i * 64 + tid] = pre[i];
      }
      if (c == 15) phase2(1);    // bp for t=1..256 from ring rows 0..255
    }
    phase2(257);                 // bp for t=257..511 (rows hold delta_256..510)

    // final argmax (first-index tie-break) + path score — f32 elementwise
    float fv = (tid < 32) ? (vdj + et[j]) : NEG_INF;
    int fi = (tid < 32) ? j : 64;
#pragma unroll
    for (int d = 32; d; d >>= 1) {
      const float ov = __shfl_xor(fv, d);
      const int oi = __shfl_xor(fi, d);
      if (ov > fv || (ov == fv && oi < fi)) { fv = ov; fi = oi; }
    }
    const int last_tag = fi;
    if (tid == 0) path_out[b] = fv;
    // ---- backtrace: 8-step jump maps (unchanged, validated) ----
    int cur[32];
#pragma unroll
    for (int e = 0; e < 32; ++e) cur[e] = (tid + 64 * e) & 31;
#pragma unroll
    for (int s = 0; s < 8; ++s) {
#pragma unroll
      for (int e = 0; e < 32; ++e) {
        const int m = (tid + 64 * e) >> 5;
        const int r = 8 * m + 7 - s;
        if (r <= T_ - 2) cur[e] = bp[r * C_ + cur[e]];
      }
    }
#pragma unroll
    for (int e = 0; e < 32; ++e) c8[tid + 64 * e] = (unsigned char)cur[e];
    if (tid == 0) {
      int c = last_tag;
      tagb[T_ - 1] = (unsigned char)c;
      for (int m = 63; m >= 0; --m) { c = c8[m * C_ + c]; btag[m] = c; }  // btag[m]=tag_{8m}
    }
    {
      const int m = tid;
      const int rhi = (m == 63) ? (T_ - 2) : (8 * m + 7);
      int c = (m == 63) ? last_tag : btag[m + 1];
#pragma unroll
      for (int s = 0; s < 7; ++s) {
        const int r = rhi - s;
        if (r >= 8 * m + 1) { c = bp[r * C_ + c]; tagb[r] = (unsigned char)c; }
      }
      tagb[8 * m] = (unsigned char)btag[m];
    }
#pragma unroll
    for (int kk = 0; kk < 8; ++kk) {
      const int t = tid + kk * 64;
      tags_out[b * T_ + t] = (float)tagb[t];
    }
  }
}

// ---------------- loss reduction ----------------
__global__ __launch_bounds__(64) void k_loss(const float* __restrict__ wsp, float* __restrict__ out0) {
  const int tid = threadIdx.x;
  float d = wsp[64 + tid] - wsp[tid];
  float m = wsp[128 + tid];
#pragma unroll
  for (int s = 32; s; s >>= 1) { d += __shfl_xor(d, s); m += __shfl_xor(m, s); }
  if (tid == 0) out0[0] = -d / m;
}

extern "C" void kernel_launch(void* const* d_in, const int* in_sizes, int n_in,
                              void* d_out, int out_size, void* d_ws, size_t ws_size,
                              hipStream_t stream) {
  (void)in_sizes; (void)n_in; (void)out_size; (void)ws_size;
  const float* vec  = (const float*)d_in[0];
  const int* mask   = (const int*)d_in[1];
  const int* tgt    = (const int*)d_in[2];
  const float* W    = (const float*)d_in[3];
  const float* bias = (const float*)d_in[4];
  const float* tr   = (const float*)d_in[5];
  const float* st   = (const float*)d_in[6];
  const float* et   = (const float*)d_in[7];
  float* out = (float*)d_out;
  float* logits = out + 1;
  float* tags = out + 1 + (size_t)B_ * T_ * C_;
  float* path = tags + (size_t)B_ * T_;
  float* wsp = (float*)d_ws;  // [0,64): logZ  [64,128): score  [128,192): mask-sum

  hipLaunchKernelGGL(k_logits, dim3(256), dim3(256), 0, stream, vec, W, bias, logits);
  hipLaunchKernelGGL(k_crf, dim3(128), dim3(64), 0, stream, logits, mask, tgt, tr, st, et, wsp, tags, path);
  hipLaunchKernelGGL(k_loss, dim3(1), dim3(64), 0, stream, wsp, out);
}

// Round 6
// 434.844 us; speedup vs baseline: 4.3687x; 1.2597x over previous
//
#include <hip/hip_runtime.h>

#define B_ 64
#define T_ 512
#define D_ 1024
#define C_ 32
#define KCH 64                // k-chunk for k_logits LDS tiling
#define NEG_INF (-1e30f)

__device__ __forceinline__ float bcast0(float v) {
  return __uint_as_float(__builtin_amdgcn_readfirstlane(__float_as_uint(v)));
}

// ---------------- logits = vectors @ W^T + b (f32, sequential-k fma chain) ----------------
// R6 rewrite: LDS-tiled. grid 256, block 256; block tile 128 rows x 32 cols,
// thread tile 4 rows (stride 32) x 4 cols (stride 8) — same mapping as before.
// K is processed in 16 chunks of 64; vec tile (128x64) and W tile (32x64) are
// staged through LDS with fully-coalesced 256B-contiguous global segments.
// +4-float row padding => the 8-row-parallel LDS reads hit banks {0,4,..,28}:
// conflict-free. Compute consumes chunks in ascending k with the SAME single
// f32 accumulator chain and fma order as all previous rounds -> logits are
// bit-identical. Pinned unroll 2 keeps ~80 live VGPRs (no spill, unlike the
// old unroll-4 flat-load version which kept 32 float4s in flight).
__global__ __launch_bounds__(256) void k_logits(const float* __restrict__ vec,
                                                const float* __restrict__ W,
                                                const float* __restrict__ bias,
                                                float* __restrict__ out) {
  __shared__ __align__(16) float vt[128][KCH + 4];  // 34816 B
  __shared__ __align__(16) float wt[32][KCH + 4];   //  8704 B
  const int tid = threadIdx.x;
  const int cg = tid & 7;   // col base 0..7  (cols cg + 8*cc)
  const int rg = tid >> 3;  // 0..31          (rows r0 + rg + 32*rr)
  const int r0 = blockIdx.x * 128;
  // staging maps
  const int sr = tid >> 4;  // 0..15  vec row within a 16-row pass
  const int sq = tid & 15;  // float4 slot in the 64-float row chunk
  const int wr = tid >> 3;  // 0..31  W row
  const int wq = tid & 7;   // two float4 slots: wq, wq+8
  float acc[4][4];
#pragma unroll
  for (int a = 0; a < 4; ++a)
#pragma unroll
    for (int bb = 0; bb < 4; ++bb) acc[a][bb] = 0.f;

  for (int c = 0; c < D_ / KCH; ++c) {
    const int k0 = c * KCH;
    __syncthreads();  // previous chunk fully consumed before overwrite
#pragma unroll
    for (int p = 0; p < 8; ++p) {  // vec tile: 8 passes x 16 rows, coalesced
      const int r = p * 16 + sr;
      float4 v = *(const float4*)(vec + (size_t)(r0 + r) * D_ + k0 + sq * 4);
      *(float4*)&vt[r][sq * 4] = v;
    }
    {  // W tile
      float4 a = *(const float4*)(W + (size_t)wr * D_ + k0 + wq * 4);
      float4 b2 = *(const float4*)(W + (size_t)wr * D_ + k0 + (wq + 8) * 4);
      *(float4*)&wt[wr][wq * 4] = a;
      *(float4*)&wt[wr][(wq + 8) * 4] = b2;
    }
    __syncthreads();
#pragma unroll 2
    for (int k = 0; k < KCH; k += 4) {
      float4 v[4], w[4];
#pragma unroll
      for (int rr = 0; rr < 4; ++rr) v[rr] = *(const float4*)&vt[rg + rr * 32][k];
#pragma unroll
      for (int cc = 0; cc < 4; ++cc) w[cc] = *(const float4*)&wt[cg + cc * 8][k];
#pragma unroll
      for (int rr = 0; rr < 4; ++rr)
#pragma unroll
        for (int cc = 0; cc < 4; ++cc) {
          acc[rr][cc] = fmaf(v[rr].x, w[cc].x, acc[rr][cc]);
          acc[rr][cc] = fmaf(v[rr].y, w[cc].y, acc[rr][cc]);
          acc[rr][cc] = fmaf(v[rr].z, w[cc].z, acc[rr][cc]);
          acc[rr][cc] = fmaf(v[rr].w, w[cc].w, acc[rr][cc]);
        }
    }
  }
#pragma unroll
  for (int rr = 0; rr < 4; ++rr) {
    const size_t row = (size_t)(r0 + rg + rr * 32);
#pragma unroll
    for (int cc = 0; cc < 4; ++cc) {
      const int c = cg + cc * 8;
      out[row * C_ + c] = acc[rr][cc] + bias[c];  // b32 store: out base only 4B-aligned
    }
  }
}

// ---------------- CRF: forward(+score) and Viterbi(+backtrace) ----------------
// R1 version (best measured k_crf: 203us, absmax 0.0078), reverted verbatim.
// grid 128 x 64 threads (one wave64 per block -> LDS in-order, no barriers).
// blocks 0..63: forward logsumexp + logZ + gold score (f32).
// blocks 64..127: f32 Viterbi — bit-replicates the np f32 DP; first-index
// tie-breaks throughout. Logits rows staged to LDS in double-buffered 64-row
// chunks (prefetch distance 64 steps); mask preloaded. Scalar b32 staging
// loads on purpose (logits = out+1 is only 4B-aligned).
__global__ __launch_bounds__(64) void k_crf(const float* __restrict__ lg,
                                            const int* __restrict__ mask,
                                            const int* __restrict__ tgt,
                                            const float* __restrict__ trans,
                                            const float* __restrict__ st,
                                            const float* __restrict__ et,
                                            float* __restrict__ wsp,
                                            float* __restrict__ tags_out,
                                            float* __restrict__ path_out) {
  __shared__ __align__(16) float a_sh[C_];
  __shared__ __align__(16) float f_sh[C_];
  __shared__ __align__(16) float Lsh[2][64 * C_];  // double-buffered 64-row logits chunks
  __shared__ int mk_sh[T_];
  __shared__ unsigned char bp[(T_ - 1) * C_];
  __shared__ unsigned char tagb[T_];
  __shared__ unsigned char c8[64 * C_];
  __shared__ int btag[64];

  const int tid = threadIdx.x;
  const int b = blockIdx.x & 63;
  const int role = blockIdx.x >> 6;
  const int j = tid & 31;
  const int h = tid >> 5;  // half: i-range [16h, 16h+16)
  const float* L = lg + (size_t)b * T_ * C_;
  const int* mk = mask + b * T_;

  // ---- stage chunk 0 (rows 0..63) + full mask into LDS ----
  float pre[32];
#pragma unroll
  for (int i = 0; i < 32; ++i) pre[i] = L[i * 64 + tid];
  {
    int4 m0 = *(const int4*)(mk + tid * 4);
    int4 m1 = *(const int4*)(mk + 256 + tid * 4);
    *(int4*)&mk_sh[tid * 4] = m0;
    *(int4*)&mk_sh[256 + tid * 4] = m1;
  }
#pragma unroll
  for (int i = 0; i < 32; ++i) Lsh[0][i * 64 + tid] = pre[i];

  if (role == 0) {
    // ================= forward + score =================
    float ET[16];
#pragma unroll
    for (int i = 0; i < 16; ++i) ET[i] = __expf(trans[(h * 16 + i) * C_ + j]);
    float alpha = (tid < 32) ? (st[j] + Lsh[0][j]) : NEG_INF;
    for (int c = 0; c < 8; ++c) {
      if (c < 7) {  // issue next chunk's loads before computing this chunk
#pragma unroll
        for (int i = 0; i < 32; ++i) pre[i] = L[(c + 1) * 2048 + i * 64 + tid];
      }
      const float* Ls = Lsh[c & 1];
      const int tlo = c ? c * 64 : 1;
      const int thi = c * 64 + 64;
      for (int t = tlo; t < thi; ++t) {
        const float lc = Ls[(t - c * 64) * C_ + j];
        const int mc = mk_sh[t];
        const float mhat = bcast0(alpha);
        const float av = __expf(alpha - mhat);
        if (tid < 32) a_sh[j] = av;
        float4 a0 = *(const float4*)&a_sh[h * 16 + 0];
        float4 a1 = *(const float4*)&a_sh[h * 16 + 4];
        float4 a2 = *(const float4*)&a_sh[h * 16 + 8];
        float4 a3 = *(const float4*)&a_sh[h * 16 + 12];
        float s0 = a0.x * ET[0], s1 = a0.y * ET[1], s2 = a0.z * ET[2], s3 = a0.w * ET[3];
        s0 = fmaf(a1.x, ET[4], s0);  s1 = fmaf(a1.y, ET[5], s1);
        s2 = fmaf(a1.z, ET[6], s2);  s3 = fmaf(a1.w, ET[7], s3);
        s0 = fmaf(a2.x, ET[8], s0);  s1 = fmaf(a2.y, ET[9], s1);
        s2 = fmaf(a2.z, ET[10], s2); s3 = fmaf(a2.w, ET[11], s3);
        s0 = fmaf(a3.x, ET[12], s0); s1 = fmaf(a3.y, ET[13], s1);
        s2 = fmaf(a3.z, ET[14], s2); s3 = fmaf(a3.w, ET[15], s3);
        float sp = (s0 + s1) + (s2 + s3);
        sp += __shfl_xor(sp, 32);
        const float anew = mhat + __logf(sp) + lc;
        if (tid < 32 && mc > 0) alpha = anew;
      }
      if (c < 7) {
#pragma unroll
        for (int i = 0; i < 32; ++i) Lsh[(c & 1) ^ 1][i * 64 + tid] = pre[i];
      }
    }
    float val = (tid < 32) ? (alpha + et[j]) : NEG_INF;
    float mm = val;
#pragma unroll
    for (int d = 32; d; d >>= 1) mm = fmaxf(mm, __shfl_xor(mm, d));
    float ee = __expf(val - mm);
#pragma unroll
    for (int d = 32; d; d >>= 1) ee += __shfl_xor(ee, d);
    const float logZ = mm + __logf(ee);
    float sc = 0.f, msf = 0.f;
#pragma unroll
    for (int kk = 0; kk < 8; ++kk) {
      const int t = tid + kk * 64;
      const float mf = (float)mk_sh[t];
      const int tg = tgt[b * T_ + t];
      msf += mf;
      float contrib = 0.f;
      if (t >= 1) contrib += trans[tgt[b * T_ + t - 1] * C_ + tg];
      if (t <= T_ - 2) contrib += L[t * C_ + tg];
      sc = fmaf(mf, contrib, sc);
    }
#pragma unroll
    for (int d = 32; d; d >>= 1) { sc += __shfl_xor(sc, d); msf += __shfl_xor(msf, d); }
    if (tid == 0) {
      int last_idx = (int)msf - 1;
      if (last_idx < 0) last_idx = 0;
      const int lt = tgt[b * T_ + last_idx];
      float s = sc + st[tgt[b * T_]] + et[lt];
      s = fmaf((float)mk_sh[T_ - 1], L[(T_ - 1) * C_ + lt], s);
      wsp[b] = logZ;
      wsp[64 + b] = s;
      wsp[128 + b] = msf;
    }
  } else {
    // ================= Viterbi (f32, np-f32-bit-replicating) =================
    float TT[16];
#pragma unroll
    for (int i = 0; i < 16; ++i) TT[i] = trans[(h * 16 + i) * C_ + j];
    float dj = st[j] + Lsh[0][j];
    if (tid < 32) f_sh[j] = dj;
    for (int c = 0; c < 8; ++c) {
      if (c < 7) {
#pragma unroll
        for (int i = 0; i < 32; ++i) pre[i] = L[(c + 1) * 2048 + i * 64 + tid];
      }
      const float* Ls = Lsh[c & 1];
      const int tlo = c ? c * 64 : 1;
      const int thi = c * 64 + 64;
      for (int t = tlo; t < thi; ++t) {
        const float lc = Ls[(t - c * 64) * C_ + j];
        const int mc = mk_sh[t];
        float dd[16];
        {
          float4 q0 = *(const float4*)&f_sh[h * 16 + 0];
          float4 q1 = *(const float4*)&f_sh[h * 16 + 4];
          float4 q2 = *(const float4*)&f_sh[h * 16 + 8];
          float4 q3 = *(const float4*)&f_sh[h * 16 + 12];
          dd[0] = q0.x;  dd[1] = q0.y;  dd[2] = q0.z;  dd[3] = q0.w;
          dd[4] = q1.x;  dd[5] = q1.y;  dd[6] = q1.z;  dd[7] = q1.w;
          dd[8] = q2.x;  dd[9] = q2.y;  dd[10] = q2.z; dd[11] = q2.w;
          dd[12] = q3.x; dd[13] = q3.y; dd[14] = q3.z; dd[15] = q3.w;
        }
        // plain f32 add (NOT fma): matches np's inner = delta + trans rounding.
        // 4 interleaved chains, ascending indices; strict '>' + index guards
        // preserve exact np.argmax first-index semantics under f32 ties.
        float v0 = dd[0] + TT[0]; int i0 = 0;
        float v1 = dd[1] + TT[1]; int i1 = 1;
        float v2 = dd[2] + TT[2]; int i2 = 2;
        float v3 = dd[3] + TT[3]; int i3 = 3;
#pragma unroll
        for (int q = 1; q < 4; ++q) {
          float c0 = dd[q * 4 + 0] + TT[q * 4 + 0]; if (c0 > v0) { v0 = c0; i0 = q * 4 + 0; }
          float c1 = dd[q * 4 + 1] + TT[q * 4 + 1]; if (c1 > v1) { v1 = c1; i1 = q * 4 + 1; }
          float c2 = dd[q * 4 + 2] + TT[q * 4 + 2]; if (c2 > v2) { v2 = c2; i2 = q * 4 + 2; }
          float c3 = dd[q * 4 + 3] + TT[q * 4 + 3]; if (c3 > v3) { v3 = c3; i3 = q * 4 + 3; }
        }
        if (v1 > v0 || (v1 == v0 && i1 < i0)) { v0 = v1; i0 = i1; }
        if (v3 > v2 || (v3 == v2 && i3 < i2)) { v2 = v3; i2 = i3; }
        if (v2 > v0 || (v2 == v0 && i2 < i0)) { v0 = v2; i0 = i2; }
        int big = h * 16 + i0;
        const float ov = __shfl_xor(v0, 32);
        const int oi = __shfl_xor(big, 32);
        if (ov > v0 || (ov == v0 && oi < big)) { v0 = ov; big = oi; }
        if (tid < 32) {
          int bpv = j;
          if (mc > 0) { dj = v0 + lc; bpv = big; }  // f32 add: matches np best+lt
          bp[(t - 1) * C_ + j] = (unsigned char)bpv;
          f_sh[j] = dj;
        }
      }
      if (c < 7) {
#pragma unroll
        for (int i = 0; i < 32; ++i) Lsh[(c & 1) ^ 1][i * 64 + tid] = pre[i];
      }
    }
    // final argmax (first-index tie-break) + path score — f32 elementwise
    float fv = (tid < 32) ? (dj + et[j]) : NEG_INF;
    int fi = (tid < 32) ? j : 64;
#pragma unroll
    for (int d = 32; d; d >>= 1) {
      const float ov = __shfl_xor(fv, d);
      const int oi = __shfl_xor(fi, d);
      if (ov > fv || (ov == fv && oi < fi)) { fv = ov; fi = oi; }
    }
    const int last_tag = fi;
    if (tid == 0) path_out[b] = fv;
    // ---- backtrace: 8-step jump maps (validated) ----
    int cur[32];
#pragma unroll
    for (int e = 0; e < 32; ++e) cur[e] = (tid + 64 * e) & 31;
#pragma unroll
    for (int s = 0; s < 8; ++s) {
#pragma unroll
      for (int e = 0; e < 32; ++e) {
        const int m = (tid + 64 * e) >> 5;
        const int r = 8 * m + 7 - s;
        if (r <= T_ - 2) cur[e] = bp[r * C_ + cur[e]];
      }
    }
#pragma unroll
    for (int e = 0; e < 32; ++e) c8[tid + 64 * e] = (unsigned char)cur[e];
    if (tid == 0) {
      int c = last_tag;
      tagb[T_ - 1] = (unsigned char)c;
      for (int m = 63; m >= 0; --m) { c = c8[m * C_ + c]; btag[m] = c; }  // btag[m]=tag_{8m}
    }
    {
      const int m = tid;
      const int rhi = (m == 63) ? (T_ - 2) : (8 * m + 7);
      int c = (m == 63) ? last_tag : btag[m + 1];
#pragma unroll
      for (int s = 0; s < 7; ++s) {
        const int r = rhi - s;
        if (r >= 8 * m + 1) { c = bp[r * C_ + c]; tagb[r] = (unsigned char)c; }
      }
      tagb[8 * m] = (unsigned char)btag[m];
    }
#pragma unroll
    for (int kk = 0; kk < 8; ++kk) {
      const int t = tid + kk * 64;
      tags_out[b * T_ + t] = (float)tagb[t];
    }
  }
}

// ---------------- loss reduction ----------------
__global__ __launch_bounds__(64) void k_loss(const float* __restrict__ wsp, float* __restrict__ out0) {
  const int tid = threadIdx.x;
  float d = wsp[64 + tid] - wsp[tid];
  float m = wsp[128 + tid];
#pragma unroll
  for (int s = 32; s; s >>= 1) { d += __shfl_xor(d, s); m += __shfl_xor(m, s); }
  if (tid == 0) out0[0] = -d / m;
}

extern "C" void kernel_launch(void* const* d_in, const int* in_sizes, int n_in,
                              void* d_out, int out_size, void* d_ws, size_t ws_size,
                              hipStream_t stream) {
  (void)in_sizes; (void)n_in; (void)out_size; (void)ws_size;
  const float* vec  = (const float*)d_in[0];
  const int* mask   = (const int*)d_in[1];
  const int* tgt    = (const int*)d_in[2];
  const float* W    = (const float*)d_in[3];
  const float* bias = (const float*)d_in[4];
  const float* tr   = (const float*)d_in[5];
  const float* st   = (const float*)d_in[6];
  const float* et   = (const float*)d_in[7];
  float* out = (float*)d_out;
  float* logits = out + 1;
  float* tags = out + 1 + (size_t)B_ * T_ * C_;
  float* path = tags + (size_t)B_ * T_;
  float* wsp = (float*)d_ws;  // [0,64): logZ  [64,128): score  [128,192): mask-sum

  hipLaunchKernelGGL(k_logits, dim3(256), dim3(256), 0, stream, vec, W, bias, logits);
  hipLaunchKernelGGL(k_crf, dim3(128), dim3(64), 0, stream, logits, mask, tgt, tr, st, et, wsp, tags, path);
  hipLaunchKernelGGL(k_loss, dim3(1), dim3(64), 0, stream, wsp, out);
}

// Round 7
// 421.285 us; speedup vs baseline: 4.5093x; 1.0322x over previous
//
#include <hip/hip_runtime.h>

#define B_ 64
#define T_ 512
#define D_ 1024
#define C_ 32
#define KCH 64                // k-chunk for k_logits LDS tiling
#define NEG_INF (-1e30f)

__device__ __forceinline__ float bcast0(float v) {
  return __uint_as_float(__builtin_amdgcn_readfirstlane(__float_as_uint(v)));
}

// ---------------- logits = vectors @ W^T + b (f32, sequential-k fma chain) ----------------
// R7: occupancy fix. R6's version was 1 block/CU = 1 wave/SIMD (grid 256 x
// block 256): every barrier stalled the whole CU and ds_read latency was
// exposed. Now BM=64, grid 512 -> 2 independent blocks/CU (2 waves/SIMD,
// separate barrier domains: one block computes while the other stages).
// LDS 26 KB/block, both fit. Per-output k-chain unchanged (full D ascending,
// single f32 accumulator, same fma order) -> logits bit-identical.
// Thread tile: 2 rows (stride 32) x 4 cols (stride 8).
__global__ __launch_bounds__(256) void k_logits(const float* __restrict__ vec,
                                                const float* __restrict__ W,
                                                const float* __restrict__ bias,
                                                float* __restrict__ out) {
  __shared__ __align__(16) float vt[64][KCH + 4];   // 17408 B
  __shared__ __align__(16) float wt[32][KCH + 4];   //  8704 B
  const int tid = threadIdx.x;
  const int cg = tid & 7;   // col base 0..7  (cols cg + 8*cc)
  const int rg = tid >> 3;  // 0..31          (rows r0 + rg + 32*rr)
  const int r0 = blockIdx.x * 64;
  // staging maps
  const int sr = tid >> 4;  // 0..15  vec rows sr + 16p
  const int sq = tid & 15;  // float4 slot in the 64-float row chunk
  const int wr = tid >> 3;  // 0..31  W row
  const int wq = tid & 7;   // two float4 slots: wq, wq+8
  float acc[2][4];
#pragma unroll
  for (int a = 0; a < 2; ++a)
#pragma unroll
    for (int bb = 0; bb < 4; ++bb) acc[a][bb] = 0.f;

  for (int c = 0; c < D_ / KCH; ++c) {
    const int k0 = c * KCH;
    __syncthreads();  // previous chunk fully consumed before overwrite
#pragma unroll
    for (int p = 0; p < 4; ++p) {  // vec tile: 4 passes x 16 rows, 256B-coalesced
      const int r = p * 16 + sr;
      float4 v = *(const float4*)(vec + (size_t)(r0 + r) * D_ + k0 + sq * 4);
      *(float4*)&vt[r][sq * 4] = v;
    }
    {  // W tile: 128B-coalesced per 8-lane group
      float4 a = *(const float4*)(W + (size_t)wr * D_ + k0 + wq * 4);
      float4 b2 = *(const float4*)(W + (size_t)wr * D_ + k0 + (wq + 8) * 4);
      *(float4*)&wt[wr][wq * 4] = a;
      *(float4*)&wt[wr][(wq + 8) * 4] = b2;
    }
    __syncthreads();
#pragma unroll 2
    for (int k = 0; k < KCH; k += 4) {
      float4 v[2], w[4];
#pragma unroll
      for (int rr = 0; rr < 2; ++rr) v[rr] = *(const float4*)&vt[rg + rr * 32][k];
#pragma unroll
      for (int cc = 0; cc < 4; ++cc) w[cc] = *(const float4*)&wt[cg + cc * 8][k];
#pragma unroll
      for (int rr = 0; rr < 2; ++rr)
#pragma unroll
        for (int cc = 0; cc < 4; ++cc) {
          acc[rr][cc] = fmaf(v[rr].x, w[cc].x, acc[rr][cc]);
          acc[rr][cc] = fmaf(v[rr].y, w[cc].y, acc[rr][cc]);
          acc[rr][cc] = fmaf(v[rr].z, w[cc].z, acc[rr][cc]);
          acc[rr][cc] = fmaf(v[rr].w, w[cc].w, acc[rr][cc]);
        }
    }
  }
#pragma unroll
  for (int rr = 0; rr < 2; ++rr) {
    const size_t row = (size_t)(r0 + rg + rr * 32);
#pragma unroll
    for (int cc = 0; cc < 4; ++cc) {
      const int c = cg + cc * 8;
      out[row * C_ + c] = acc[rr][cc] + bias[c];  // b32 store: out base only 4B-aligned
    }
  }
}

// ---------------- CRF: forward(+score) and Viterbi(+backtrace) ----------------
// R1 version (best measured k_crf across 6 structural variants: 203-222us,
// absmax 0.0078), kept verbatim.
// grid 128 x 64 threads (one wave64 per block -> LDS in-order, no barriers).
// blocks 0..63: forward logsumexp + logZ + gold score (f32).
// blocks 64..127: f32 Viterbi — bit-replicates the np f32 DP; first-index
// tie-breaks throughout. Logits rows staged to LDS in double-buffered 64-row
// chunks (prefetch distance 64 steps); mask preloaded. Scalar b32 staging
// loads on purpose (logits = out+1 is only 4B-aligned).
__global__ __launch_bounds__(64) void k_crf(const float* __restrict__ lg,
                                            const int* __restrict__ mask,
                                            const int* __restrict__ tgt,
                                            const float* __restrict__ trans,
                                            const float* __restrict__ st,
                                            const float* __restrict__ et,
                                            float* __restrict__ wsp,
                                            float* __restrict__ tags_out,
                                            float* __restrict__ path_out) {
  __shared__ __align__(16) float a_sh[C_];
  __shared__ __align__(16) float f_sh[C_];
  __shared__ __align__(16) float Lsh[2][64 * C_];  // double-buffered 64-row logits chunks
  __shared__ int mk_sh[T_];
  __shared__ unsigned char bp[(T_ - 1) * C_];
  __shared__ unsigned char tagb[T_];
  __shared__ unsigned char c8[64 * C_];
  __shared__ int btag[64];

  const int tid = threadIdx.x;
  const int b = blockIdx.x & 63;
  const int role = blockIdx.x >> 6;
  const int j = tid & 31;
  const int h = tid >> 5;  // half: i-range [16h, 16h+16)
  const float* L = lg + (size_t)b * T_ * C_;
  const int* mk = mask + b * T_;

  // ---- stage chunk 0 (rows 0..63) + full mask into LDS ----
  float pre[32];
#pragma unroll
  for (int i = 0; i < 32; ++i) pre[i] = L[i * 64 + tid];
  {
    int4 m0 = *(const int4*)(mk + tid * 4);
    int4 m1 = *(const int4*)(mk + 256 + tid * 4);
    *(int4*)&mk_sh[tid * 4] = m0;
    *(int4*)&mk_sh[256 + tid * 4] = m1;
  }
#pragma unroll
  for (int i = 0; i < 32; ++i) Lsh[0][i * 64 + tid] = pre[i];

  if (role == 0) {
    // ================= forward + score =================
    float ET[16];
#pragma unroll
    for (int i = 0; i < 16; ++i) ET[i] = __expf(trans[(h * 16 + i) * C_ + j]);
    float alpha = (tid < 32) ? (st[j] + Lsh[0][j]) : NEG_INF;
    for (int c = 0; c < 8; ++c) {
      if (c < 7) {  // issue next chunk's loads before computing this chunk
#pragma unroll
        for (int i = 0; i < 32; ++i) pre[i] = L[(c + 1) * 2048 + i * 64 + tid];
      }
      const float* Ls = Lsh[c & 1];
      const int tlo = c ? c * 64 : 1;
      const int thi = c * 64 + 64;
      for (int t = tlo; t < thi; ++t) {
        const float lc = Ls[(t - c * 64) * C_ + j];
        const int mc = mk_sh[t];
        const float mhat = bcast0(alpha);
        const float av = __expf(alpha - mhat);
        if (tid < 32) a_sh[j] = av;
        float4 a0 = *(const float4*)&a_sh[h * 16 + 0];
        float4 a1 = *(const float4*)&a_sh[h * 16 + 4];
        float4 a2 = *(const float4*)&a_sh[h * 16 + 8];
        float4 a3 = *(const float4*)&a_sh[h * 16 + 12];
        float s0 = a0.x * ET[0], s1 = a0.y * ET[1], s2 = a0.z * ET[2], s3 = a0.w * ET[3];
        s0 = fmaf(a1.x, ET[4], s0);  s1 = fmaf(a1.y, ET[5], s1);
        s2 = fmaf(a1.z, ET[6], s2);  s3 = fmaf(a1.w, ET[7], s3);
        s0 = fmaf(a2.x, ET[8], s0);  s1 = fmaf(a2.y, ET[9], s1);
        s2 = fmaf(a2.z, ET[10], s2); s3 = fmaf(a2.w, ET[11], s3);
        s0 = fmaf(a3.x, ET[12], s0); s1 = fmaf(a3.y, ET[13], s1);
        s2 = fmaf(a3.z, ET[14], s2); s3 = fmaf(a3.w, ET[15], s3);
        float sp = (s0 + s1) + (s2 + s3);
        sp += __shfl_xor(sp, 32);
        const float anew = mhat + __logf(sp) + lc;
        if (tid < 32 && mc > 0) alpha = anew;
      }
      if (c < 7) {
#pragma unroll
        for (int i = 0; i < 32; ++i) Lsh[(c & 1) ^ 1][i * 64 + tid] = pre[i];
      }
    }
    float val = (tid < 32) ? (alpha + et[j]) : NEG_INF;
    float mm = val;
#pragma unroll
    for (int d = 32; d; d >>= 1) mm = fmaxf(mm, __shfl_xor(mm, d));
    float ee = __expf(val - mm);
#pragma unroll
    for (int d = 32; d; d >>= 1) ee += __shfl_xor(ee, d);
    const float logZ = mm + __logf(ee);
    float sc = 0.f, msf = 0.f;
#pragma unroll
    for (int kk = 0; kk < 8; ++kk) {
      const int t = tid + kk * 64;
      const float mf = (float)mk_sh[t];
      const int tg = tgt[b * T_ + t];
      msf += mf;
      float contrib = 0.f;
      if (t >= 1) contrib += trans[tgt[b * T_ + t - 1] * C_ + tg];
      if (t <= T_ - 2) contrib += L[t * C_ + tg];
      sc = fmaf(mf, contrib, sc);
    }
#pragma unroll
    for (int d = 32; d; d >>= 1) { sc += __shfl_xor(sc, d); msf += __shfl_xor(msf, d); }
    if (tid == 0) {
      int last_idx = (int)msf - 1;
      if (last_idx < 0) last_idx = 0;
      const int lt = tgt[b * T_ + last_idx];
      float s = sc + st[tgt[b * T_]] + et[lt];
      s = fmaf((float)mk_sh[T_ - 1], L[(T_ - 1) * C_ + lt], s);
      wsp[b] = logZ;
      wsp[64 + b] = s;
      wsp[128 + b] = msf;
    }
  } else {
    // ================= Viterbi (f32, np-f32-bit-replicating) =================
    float TT[16];
#pragma unroll
    for (int i = 0; i < 16; ++i) TT[i] = trans[(h * 16 + i) * C_ + j];
    float dj = st[j] + Lsh[0][j];
    if (tid < 32) f_sh[j] = dj;
    for (int c = 0; c < 8; ++c) {
      if (c < 7) {
#pragma unroll
        for (int i = 0; i < 32; ++i) pre[i] = L[(c + 1) * 2048 + i * 64 + tid];
      }
      const float* Ls = Lsh[c & 1];
      const int tlo = c ? c * 64 : 1;
      const int thi = c * 64 + 64;
      for (int t = tlo; t < thi; ++t) {
        const float lc = Ls[(t - c * 64) * C_ + j];
        const int mc = mk_sh[t];
        float dd[16];
        {
          float4 q0 = *(const float4*)&f_sh[h * 16 + 0];
          float4 q1 = *(const float4*)&f_sh[h * 16 + 4];
          float4 q2 = *(const float4*)&f_sh[h * 16 + 8];
          float4 q3 = *(const float4*)&f_sh[h * 16 + 12];
          dd[0] = q0.x;  dd[1] = q0.y;  dd[2] = q0.z;  dd[3] = q0.w;
          dd[4] = q1.x;  dd[5] = q1.y;  dd[6] = q1.z;  dd[7] = q1.w;
          dd[8] = q2.x;  dd[9] = q2.y;  dd[10] = q2.z; dd[11] = q2.w;
          dd[12] = q3.x; dd[13] = q3.y; dd[14] = q3.z; dd[15] = q3.w;
        }
        // plain f32 add (NOT fma): matches np's inner = delta + trans rounding.
        // 4 interleaved chains, ascending indices; strict '>' + index guards
        // preserve exact np.argmax first-index semantics under f32 ties.
        float v0 = dd[0] + TT[0]; int i0 = 0;
        float v1 = dd[1] + TT[1]; int i1 = 1;
        float v2 = dd[2] + TT[2]; int i2 = 2;
        float v3 = dd[3] + TT[3]; int i3 = 3;
#pragma unroll
        for (int q = 1; q < 4; ++q) {
          float c0 = dd[q * 4 + 0] + TT[q * 4 + 0]; if (c0 > v0) { v0 = c0; i0 = q * 4 + 0; }
          float c1 = dd[q * 4 + 1] + TT[q * 4 + 1]; if (c1 > v1) { v1 = c1; i1 = q * 4 + 1; }
          float c2 = dd[q * 4 + 2] + TT[q * 4 + 2]; if (c2 > v2) { v2 = c2; i2 = q * 4 + 2; }
          float c3 = dd[q * 4 + 3] + TT[q * 4 + 3]; if (c3 > v3) { v3 = c3; i3 = q * 4 + 3; }
        }
        if (v1 > v0 || (v1 == v0 && i1 < i0)) { v0 = v1; i0 = i1; }
        if (v3 > v2 || (v3 == v2 && i3 < i2)) { v2 = v3; i2 = i3; }
        if (v2 > v0 || (v2 == v0 && i2 < i0)) { v0 = v2; i0 = i2; }
        int big = h * 16 + i0;
        const float ov = __shfl_xor(v0, 32);
        const int oi = __shfl_xor(big, 32);
        if (ov > v0 || (ov == v0 && oi < big)) { v0 = ov; big = oi; }
        if (tid < 32) {
          int bpv = j;
          if (mc > 0) { dj = v0 + lc; bpv = big; }  // f32 add: matches np best+lt
          bp[(t - 1) * C_ + j] = (unsigned char)bpv;
          f_sh[j] = dj;
        }
      }
      if (c < 7) {
#pragma unroll
        for (int i = 0; i < 32; ++i) Lsh[(c & 1) ^ 1][i * 64 + tid] = pre[i];
      }
    }
    // final argmax (first-index tie-break) + path score — f32 elementwise
    float fv = (tid < 32) ? (dj + et[j]) : NEG_INF;
    int fi = (tid < 32) ? j : 64;
#pragma unroll
    for (int d = 32; d; d >>= 1) {
      const float ov = __shfl_xor(fv, d);
      const int oi = __shfl_xor(fi, d);
      if (ov > fv || (ov == fv && oi < fi)) { fv = ov; fi = oi; }
    }
    const int last_tag = fi;
    if (tid == 0) path_out[b] = fv;
    // ---- backtrace: 8-step jump maps (validated) ----
    int cur[32];
#pragma unroll
    for (int e = 0; e < 32; ++e) cur[e] = (tid + 64 * e) & 31;
#pragma unroll
    for (int s = 0; s < 8; ++s) {
#pragma unroll
      for (int e = 0; e < 32; ++e) {
        const int m = (tid + 64 * e) >> 5;
        const int r = 8 * m + 7 - s;
        if (r <= T_ - 2) cur[e] = bp[r * C_ + cur[e]];
      }
    }
#pragma unroll
    for (int e = 0; e < 32; ++e) c8[tid + 64 * e] = (unsigned char)cur[e];
    if (tid == 0) {
      int c = last_tag;
      tagb[T_ - 1] = (unsigned char)c;
      for (int m = 63; m >= 0; --m) { c = c8[m * C_ + c]; btag[m] = c; }  // btag[m]=tag_{8m}
    }
    {
      const int m = tid;
      const int rhi = (m == 63) ? (T_ - 2) : (8 * m + 7);
      int c = (m == 63) ? last_tag : btag[m + 1];
#pragma unroll
      for (int s = 0; s < 7; ++s) {
        const int r = rhi - s;
        if (r >= 8 * m + 1) { c = bp[r * C_ + c]; tagb[r] = (unsigned char)c; }
      }
      tagb[8 * m] = (unsigned char)btag[m];
    }
#pragma unroll
    for (int kk = 0; kk < 8; ++kk) {
      const int t = tid + kk * 64;
      tags_out[b * T_ + t] = (float)tagb[t];
    }
  }
}

// ---------------- loss reduction ----------------
__global__ __launch_bounds__(64) void k_loss(const float* __restrict__ wsp, float* __restrict__ out0) {
  const int tid = threadIdx.x;
  float d = wsp[64 + tid] - wsp[tid];
  float m = wsp[128 + tid];
#pragma unroll
  for (int s = 32; s; s >>= 1) { d += __shfl_xor(d, s); m += __shfl_xor(m, s); }
  if (tid == 0) out0[0] = -d / m;
}

extern "C" void kernel_launch(void* const* d_in, const int* in_sizes, int n_in,
                              void* d_out, int out_size, void* d_ws, size_t ws_size,
                              hipStream_t stream) {
  (void)in_sizes; (void)n_in; (void)out_size; (void)ws_size;
  const float* vec  = (const float*)d_in[0];
  const int* mask   = (const int*)d_in[1];
  const int* tgt    = (const int*)d_in[2];
  const float* W    = (const float*)d_in[3];
  const float* bias = (const float*)d_in[4];
  const float* tr   = (const float*)d_in[5];
  const float* st   = (const float*)d_in[6];
  const float* et   = (const float*)d_in[7];
  float* out = (float*)d_out;
  float* logits = out + 1;
  float* tags = out + 1 + (size_t)B_ * T_ * C_;
  float* path = tags + (size_t)B_ * T_;
  float* wsp = (float*)d_ws;  // [0,64): logZ  [64,128): score  [128,192): mask-sum

  hipLaunchKernelGGL(k_logits, dim3(512), dim3(256), 0, stream, vec, W, bias, logits);
  hipLaunchKernelGGL(k_crf, dim3(128), dim3(64), 0, stream, logits, mask, tgt, tr, st, et, wsp, tags, path);
  hipLaunchKernelGGL(k_loss, dim3(1), dim3(64), 0, stream, wsp, out);
}